// Round 2
// baseline (2925.734 us; speedup 1.0000x reference)
//
#include <hip/hip_runtime.h>

#define NN 50000
#define EE 100000
#define HIDD 128
#define HH 4
#define CCC 128
#define HCC 512
#define LLL 3
#define SCALE 0.08838834764831845f

typedef unsigned short u16;
typedef unsigned int u32;

__device__ __forceinline__ float bfl(u32 u){ return __uint_as_float(u << 16); }
__device__ __forceinline__ float bfh(u32 u){ return __uint_as_float(u & 0xffff0000u); }
__device__ __forceinline__ u16 f2bf(float f){
  u32 u = __float_as_uint(f);
  return (u16)((u + 0x7fffu + ((u >> 16) & 1u)) >> 16);
}
__device__ __forceinline__ u32 pack2(float a, float b){
  return (u32)f2bf(a) | ((u32)f2bf(b) << 16);
}
__device__ __forceinline__ void atomic_pk_bf16(u16* addr, float a, float b){
  u32 v = pack2(a, b);
  asm volatile("global_atomic_pk_add_bf16 %0, %1, off" :: "v"(addr), "v"(v) : "memory");
}

__global__ __launch_bounds__(256) void kzero(float* p, int n){
  int i = blockIdx.x * 256 + threadIdx.x;
  if (i < n) p[i] = 0.f;
}

// K1: fused GEMM  out[N, 2048] = x[N,128] @ [Wq|Wk|Wv|Wskip] + bias -> bf16
// 32x64 tile per block; LDS = 51.7 KB (under 64 KB static limit)
__global__ __launch_bounds__(256) void k1_qkvs(
    const float* __restrict__ x,
    const float* __restrict__ Wq, const float* __restrict__ Wk,
    const float* __restrict__ Wv, const float* __restrict__ Ws,
    const float* __restrict__ bq, const float* __restrict__ bk,
    const float* __restrict__ bv, const float* __restrict__ bs,
    u16* __restrict__ qo, u16* __restrict__ ko, u16* __restrict__ vo,
    u16* __restrict__ agg)
{
  __shared__ float xs[32][132];
  __shared__ float ws[128][68];
  const int t = threadIdx.x;
  const int n0 = blockIdx.x * 32;
  const int ct = blockIdx.y;
  const int m = ct >> 3;
  const int colbase = (ct & 7) * 64;
  const float* W    = (m==0)?Wq:(m==1)?Wk:(m==2)?Wv:Ws;
  const float* bias = (m==0)?bq:(m==1)?bk:(m==2)?bv:bs;

  #pragma unroll
  for (int i = 0; i < 4; ++i) {
    int f = t + 256*i;
    int r = f >> 5, c4 = (f & 31) * 4;
    float4 v = make_float4(0.f,0.f,0.f,0.f);
    if (n0 + r < NN) v = *(const float4*)(x + (size_t)(n0+r)*HIDD + c4);
    *(float4*)&xs[r][c4] = v;
  }
  #pragma unroll
  for (int i = 0; i < 8; ++i) {
    int f = t + 256*i;
    int k = f >> 4, c4 = (f & 15) * 4;
    *(float4*)&ws[k][c4] = *(const float4*)(W + (size_t)k*HCC + colbase + c4);
  }
  __syncthreads();

  const int tx = t & 15, ty = t >> 4;
  float acc[2][4] = {};
  #pragma unroll 4
  for (int k = 0; k < 128; ++k) {
    float4 b = *(const float4*)&ws[k][tx*4];
    float a0 = xs[ty*2+0][k];
    float a1 = xs[ty*2+1][k];
    acc[0][0]+=a0*b.x; acc[0][1]+=a0*b.y; acc[0][2]+=a0*b.z; acc[0][3]+=a0*b.w;
    acc[1][0]+=a1*b.x; acc[1][1]+=a1*b.y; acc[1][2]+=a1*b.z; acc[1][3]+=a1*b.w;
  }

  float4 bb = *(const float4*)(bias + colbase + tx*4);
  u16* outp = (m==0)?qo:(m==1)?ko:(m==2)?vo:agg;
  #pragma unroll
  for (int i = 0; i < 2; ++i) {
    int n = n0 + ty*2 + i;
    if (n >= NN) continue;
    float o0 = acc[i][0]+bb.x, o1 = acc[i][1]+bb.y;
    float o2 = acc[i][2]+bb.z, o3 = acc[i][3]+bb.w;
    size_t base = (size_t)n*HCC + colbase + tx*4;
    *(uint2*)(outp + base) = make_uint2(pack2(o0,o1), pack2(o2,o3));
  }
}

// K1b: qWe[n,h] = sum_c q[n,h,c]*We[h,c]
__global__ __launch_bounds__(256) void k1b_qwe(
    const u16* __restrict__ q, const float* __restrict__ We,
    float* __restrict__ qWe)
{
  int wave = threadIdx.x >> 6, lane = threadIdx.x & 63;
  int n = blockIdx.x * 4 + wave;
  if (n >= NN) return;
  int h = lane >> 4, c0 = (lane & 15) * 8;
  uint4 qa = *(const uint4*)(q + (size_t)n*HCC + h*CCC + c0);
  const float* wr = We + h*CCC + c0;
  float s = bfl(qa.x)*wr[0] + bfh(qa.x)*wr[1]
          + bfl(qa.y)*wr[2] + bfh(qa.y)*wr[3]
          + bfl(qa.z)*wr[4] + bfh(qa.z)*wr[5]
          + bfl(qa.w)*wr[6] + bfh(qa.w)*wr[7];
  #pragma unroll
  for (int off = 8; off; off >>= 1) s += __shfl_xor(s, off);
  if ((lane & 15) == 0) qWe[(size_t)n*HH + h] = s;
}

// K2: p = exp(scale*(q[dst].k[src] + w_e*qWe[dst])); atomic denom
__global__ __launch_bounds__(256) void k2_alpha(
    const u16* __restrict__ q, const u16* __restrict__ k,
    const int* __restrict__ ei, const float* __restrict__ ea,
    const float* __restrict__ qWe,
    float* __restrict__ pbuf, float* __restrict__ denom)
{
  int wave = threadIdx.x >> 6, lane = threadIdx.x & 63;
  int e = blockIdx.x * 4 + wave;
  if (e >= EE) return;
  int src = ei[e], dst = ei[EE + e];
  int h = lane >> 4, c0 = (lane & 15) * 8;
  uint4 qa = *(const uint4*)(q + (size_t)dst*HCC + h*CCC + c0);
  uint4 ka = *(const uint4*)(k + (size_t)src*HCC + h*CCC + c0);
  float s = bfl(qa.x)*bfl(ka.x) + bfh(qa.x)*bfh(ka.x)
          + bfl(qa.y)*bfl(ka.y) + bfh(qa.y)*bfh(ka.y)
          + bfl(qa.z)*bfl(ka.z) + bfh(qa.z)*bfh(ka.z)
          + bfl(qa.w)*bfl(ka.w) + bfh(qa.w)*bfh(ka.w);
  #pragma unroll
  for (int off = 8; off; off >>= 1) s += __shfl_xor(s, off);
  if ((lane & 15) == 0) {
    float alpha = (s + ea[e] * qWe[(size_t)dst*HH + h]) * SCALE;
    float p = expf(alpha);
    pbuf[(size_t)e*HH + h] = p;
    atomicAdd(&denom[(size_t)dst*HH + h], p);
  }
}

// K3: a = p/(denom+1e-16); agg[dst] += a*v[src] (pk bf16 atomics); sE[dst] += a*w_e
__global__ __launch_bounds__(256) void k3_msg(
    const u16* __restrict__ v, const int* __restrict__ ei,
    const float* __restrict__ ea, const float* __restrict__ pbuf,
    const float* __restrict__ denom,
    u16* __restrict__ agg, float* __restrict__ sE)
{
  int wave = threadIdx.x >> 6, lane = threadIdx.x & 63;
  int e = blockIdx.x * 4 + wave;
  if (e >= EE) return;
  int src = ei[e], dst = ei[EE + e];
  int h = lane >> 4, c0 = (lane & 15) * 8;
  float p = pbuf[(size_t)e*HH + h];
  float d = denom[(size_t)dst*HH + h];
  float a = p / (d + 1e-16f);
  uint4 va = *(const uint4*)(v + (size_t)src*HCC + h*CCC + c0);
  u16* base = agg + (size_t)dst*HCC + h*CCC + c0;
  atomic_pk_bf16(base+0, a*bfl(va.x), a*bfh(va.x));
  atomic_pk_bf16(base+2, a*bfl(va.y), a*bfh(va.y));
  atomic_pk_bf16(base+4, a*bfl(va.z), a*bfh(va.z));
  atomic_pk_bf16(base+6, a*bfl(va.w), a*bfh(va.w));
  if ((lane & 15) == 0) atomicAdd(&sE[(size_t)dst*HH + h], a * ea[e]);
}

// K4: conv = agg + sE*We ; h = elu(conv@Wproj + bproj) ; y = x + h ; LayerNorm
__global__ __launch_bounds__(256) void k4_out(
    const u16* __restrict__ agg, const float* __restrict__ sE,
    const float* __restrict__ We, const float* __restrict__ Wp,
    const float* __restrict__ bp, const float* __restrict__ gamma,
    const float* __restrict__ beta, const float* x_in,
    float* x_out)
{
  __shared__ float convs[32][68];
  __shared__ float wp[64][132];
  __shared__ float ytile[32][132];
  __shared__ float mu_s[32], rs_s[32];
  const int t = threadIdx.x;
  const int n0 = blockIdx.x * 32;
  const int tx = t & 31, ty = t >> 5;
  float acc[4][4] = {};

  for (int kc = 0; kc < 8; ++kc) {
    int k0 = kc * 64;
    int h = kc >> 1;
    {
      int r = t >> 3, c8 = (t & 7) * 8;
      int n = n0 + r;
      float cv[8] = {0.f,0.f,0.f,0.f,0.f,0.f,0.f,0.f};
      if (n < NN) {
        uint4 av = *(const uint4*)(agg + (size_t)n*HCC + k0 + c8);
        float s = sE[(size_t)n*HH + h];
        const float* wv = We + k0 + c8;
        cv[0]=bfl(av.x)+s*wv[0]; cv[1]=bfh(av.x)+s*wv[1];
        cv[2]=bfl(av.y)+s*wv[2]; cv[3]=bfh(av.y)+s*wv[3];
        cv[4]=bfl(av.z)+s*wv[4]; cv[5]=bfh(av.z)+s*wv[5];
        cv[6]=bfl(av.w)+s*wv[6]; cv[7]=bfh(av.w)+s*wv[7];
      }
      *(float4*)&convs[r][c8]   = make_float4(cv[0],cv[1],cv[2],cv[3]);
      *(float4*)&convs[r][c8+4] = make_float4(cv[4],cv[5],cv[6],cv[7]);
    }
    #pragma unroll
    for (int i = 0; i < 8; ++i) {
      int f = t + 256*i;
      int kk = f >> 5, j4 = (f & 31) * 4;
      *(float4*)&wp[kk][j4] = *(const float4*)(Wp + (size_t)(k0+kk)*HIDD + j4);
    }
    __syncthreads();
    #pragma unroll 8
    for (int kk = 0; kk < 64; ++kk) {
      float4 b = *(const float4*)&wp[kk][tx*4];
      float a[4];
      a[0] = convs[ty*4+0][kk];
      a[1] = convs[ty*4+1][kk];
      a[2] = convs[ty*4+2][kk];
      a[3] = convs[ty*4+3][kk];
      #pragma unroll
      for (int i = 0; i < 4; ++i) {
        acc[i][0] += a[i]*b.x; acc[i][1] += a[i]*b.y;
        acc[i][2] += a[i]*b.z; acc[i][3] += a[i]*b.w;
      }
    }
    __syncthreads();
  }

  float4 bb = *(const float4*)(bp + tx*4);
  #pragma unroll
  for (int i = 0; i < 4; ++i) {
    int r = ty*4 + i;
    int n = n0 + r;
    float4 xv = make_float4(0.f,0.f,0.f,0.f);
    if (n < NN) xv = *(const float4*)(x_in + (size_t)n*HIDD + tx*4);
    float h0 = acc[i][0]+bb.x; h0 = h0 > 0.f ? h0 : expm1f(h0);
    float h1 = acc[i][1]+bb.y; h1 = h1 > 0.f ? h1 : expm1f(h1);
    float h2 = acc[i][2]+bb.z; h2 = h2 > 0.f ? h2 : expm1f(h2);
    float h3 = acc[i][3]+bb.w; h3 = h3 > 0.f ? h3 : expm1f(h3);
    ytile[r][tx*4+0] = xv.x + h0;
    ytile[r][tx*4+1] = xv.y + h1;
    ytile[r][tx*4+2] = xv.z + h2;
    ytile[r][tx*4+3] = xv.w + h3;
  }
  __syncthreads();

  {
    int r = t >> 3, seg = t & 7;
    float s = 0.f, s2 = 0.f;
    #pragma unroll
    for (int j = 0; j < 16; ++j) {
      float y = ytile[r][seg*16 + j];
      s += y; s2 += y*y;
    }
    #pragma unroll
    for (int off = 4; off; off >>= 1) { s += __shfl_xor(s, off); s2 += __shfl_xor(s2, off); }
    if (seg == 0) {
      float mu = s * (1.f/128.f);
      float var = s2 * (1.f/128.f) - mu*mu;
      mu_s[r] = mu;
      rs_s[r] = rsqrtf(var + 1e-5f);
    }
  }
  __syncthreads();

  #pragma unroll
  for (int i = 0; i < 4; ++i) {
    int f = t + 256*i;
    int r = f >> 5, c4 = (f & 31) * 4;
    int n = n0 + r;
    if (n >= NN) continue;
    float mu = mu_s[r], rs = rs_s[r];
    float4 g  = *(const float4*)(gamma + c4);
    float4 bt = *(const float4*)(beta + c4);
    float4 yv = *(float4*)&ytile[r][c4];
    float4 o = make_float4((yv.x-mu)*rs*g.x + bt.x,
                           (yv.y-mu)*rs*g.y + bt.y,
                           (yv.z-mu)*rs*g.z + bt.z,
                           (yv.w-mu)*rs*g.w + bt.w);
    *(float4*)(x_out + (size_t)n*HIDD + c4) = o;
  }
}

extern "C" void kernel_launch(void* const* d_in, const int* in_sizes, int n_in,
                              void* d_out, int out_size, void* d_ws, size_t ws_size,
                              hipStream_t stream)
{
  const float* x    = (const float*)d_in[0];
  const int*   ei   = (const int*)d_in[1];
  const float* ea   = (const float*)d_in[2];
  const float* Wq   = (const float*)d_in[3];
  const float* bq   = (const float*)d_in[4];
  const float* Wk   = (const float*)d_in[5];
  const float* bk   = (const float*)d_in[6];
  const float* Wv   = (const float*)d_in[7];
  const float* bv   = (const float*)d_in[8];
  const float* We   = (const float*)d_in[9];
  const float* Wsk  = (const float*)d_in[10];
  const float* bsk  = (const float*)d_in[11];
  const float* Wp   = (const float*)d_in[12];
  const float* bp   = (const float*)d_in[13];
  const float* gamma= (const float*)d_in[14];
  const float* beta = (const float*)d_in[15];

  char* wsb = (char*)d_ws;
  size_t off = 0;
  auto alloc = [&](size_t bytes) -> void* {
    void* p = wsb + off;
    off += (bytes + 255) & ~(size_t)255;
    return p;
  };
  u16*   qb     = (u16*)  alloc((size_t)NN*HCC*2);   // 51.2 MB
  u16*   kb     = (u16*)  alloc((size_t)NN*HCC*2);   // 51.2 MB
  u16*   vb     = (u16*)  alloc((size_t)NN*HCC*2);   // 51.2 MB
  u16*   aggb   = (u16*)  alloc((size_t)NN*HCC*2);   // 51.2 MB
  float* pbuf   = (float*)alloc((size_t)EE*HH*4);    // 1.6 MB
  float* denomsE= (float*)alloc((size_t)2*NN*HH*4);  // 1.6 MB
  float* denom  = denomsE;
  float* sE     = denomsE + (size_t)NN*HH;
  float* qWe    = (float*)alloc((size_t)NN*HH*4);    // 0.8 MB
  float* xio    = (float*)d_out;                     // inter-layer x buffer

  const dim3 g1((NN + 31)/32, 32);
  const int gz   = (2*NN*HH + 255)/256;
  const int gb1b = (NN + 3)/4;
  const int ge   = (EE + 3)/4;
  const int g4   = (NN + 31)/32;

  for (int l = 0; l < LLL; ++l) {
    const float* Wq_l  = Wq  + (size_t)l*HIDD*HCC;
    const float* Wk_l  = Wk  + (size_t)l*HIDD*HCC;
    const float* Wv_l  = Wv  + (size_t)l*HIDD*HCC;
    const float* Wsk_l = Wsk + (size_t)l*HIDD*HCC;
    const float* bq_l  = bq  + (size_t)l*HCC;
    const float* bk_l  = bk  + (size_t)l*HCC;
    const float* bv_l  = bv  + (size_t)l*HCC;
    const float* bsk_l = bsk + (size_t)l*HCC;
    const float* We_l  = We  + (size_t)l*HCC;
    const float* Wp_l  = Wp  + (size_t)l*HCC*HIDD;
    const float* bp_l  = bp  + (size_t)l*HIDD;
    const float* g_l   = gamma + (size_t)l*HIDD;
    const float* b_l   = beta  + (size_t)l*HIDD;

    const float* xin = (l == 0) ? x : xio;

    k1_qkvs<<<g1, 256, 0, stream>>>(xin, Wq_l, Wk_l, Wv_l, Wsk_l,
                                    bq_l, bk_l, bv_l, bsk_l, qb, kb, vb, aggb);
    k1b_qwe<<<gb1b, 256, 0, stream>>>(qb, We_l, qWe);
    kzero<<<gz, 256, 0, stream>>>(denomsE, 2*NN*HH);
    k2_alpha<<<ge, 256, 0, stream>>>(qb, kb, ei, ea, qWe, pbuf, denom);
    k3_msg<<<ge, 256, 0, stream>>>(vb, ei, ea, pbuf, denom, aggb, sE);
    k4_out<<<g4, 256, 0, stream>>>(aggb, sE, We_l, Wp_l, bp_l, g_l, b_l, xin, xio);
  }
}

// Round 3
// 1738.614 us; speedup vs baseline: 1.6828x; 1.6828x over previous
//
#include <hip/hip_runtime.h>

#define NN 50000
#define EE 100000
#define HIDD 128
#define HH 4
#define CCC 128
#define HCC 512
#define QS 2048            // row stride of fused qkvs buffer
#define LLL 3
#define SCALE 0.08838834764831845f

typedef unsigned short u16;
typedef unsigned int u32;
typedef __attribute__((ext_vector_type(8))) short bfrag;   // 8 x bf16
typedef __attribute__((ext_vector_type(4))) float fx4;

__device__ __forceinline__ float bfl(u32 u){ return __uint_as_float(u << 16); }
__device__ __forceinline__ float bfh(u32 u){ return __uint_as_float(u & 0xffff0000u); }
__device__ __forceinline__ u16 f2bf(float f){
  u32 u = __float_as_uint(f);
  return (u16)((u + 0x7fffu + ((u >> 16) & 1u)) >> 16);
}
__device__ __forceinline__ u32 pack2(float a, float b){
  return (u32)f2bf(a) | ((u32)f2bf(b) << 16);
}
__device__ __forceinline__ void atomic_pk_bf16(u16* addr, float a, float b){
  u32 v = pack2(a, b);
  asm volatile("global_atomic_pk_add_bf16 %0, %1, off" :: "v"(addr), "v"(v) : "memory");
}

__global__ __launch_bounds__(256) void kzero(float* p, int n){
  int i = blockIdx.x * 256 + threadIdx.x;
  if (i < n) p[i] = 0.f;
}

// per-layer weight prep: Wt[2048][128] bf16 (transposed [Wq|Wk|Wv|Ws]),
// Wpt[128][512] bf16 (transposed Wproj), bias_cat[2048] f32
__global__ __launch_bounds__(256) void kprep(
    const float* __restrict__ Wq, const float* __restrict__ Wk,
    const float* __restrict__ Wv, const float* __restrict__ Ws,
    const float* __restrict__ bq, const float* __restrict__ bk,
    const float* __restrict__ bv, const float* __restrict__ bs,
    const float* __restrict__ Wp,
    u16* __restrict__ Wt, u16* __restrict__ Wpt, float* __restrict__ bias_cat)
{
  int id = blockIdx.x * 256 + threadIdx.x;
  if (id < 2048*128) {
    int n = id >> 7, k = id & 127;
    int m = n >> 9, nc = n & 511;
    const float* W = (m==0)?Wq:(m==1)?Wk:(m==2)?Wv:Ws;
    Wt[id] = f2bf(W[(size_t)k*HCC + nc]);
  } else if (id < 2048*128 + 128*512) {
    int j = id - 2048*128;
    int n = j >> 9, k = j & 511;
    Wpt[j] = f2bf(Wp[(size_t)k*HIDD + n]);
  } else if (id < 2048*128 + 128*512 + 2048) {
    int n = id - (2048*128 + 128*512);
    int m = n >> 9, nc = n & 511;
    const float* b = (m==0)?bq:(m==1)?bk:(m==2)?bv:bs;
    bias_cat[n] = b[nc];
  }
}

// K1: qkvs[N,2048] = bf16( x[N,128] @ Wt^T + bias )   (q|k|v|agg fused)
// block tile 64 rows x 256 cols, 4 waves, MFMA 16x16x32 bf16
__global__ __launch_bounds__(256) void k1_mfma(
    const float* __restrict__ x, const u16* __restrict__ Wt,
    const float* __restrict__ bias, u16* __restrict__ qkvs)
{
  __shared__ u16 xs[64][136];     // x tile bf16, padded
  __shared__ u16 outs[64][264];   // output staging, padded
  const int t = threadIdx.x;
  const int cb = blockIdx.x * 256;   // col block (fastest -> x-tile reuse)
  const int n0 = blockIdx.y * 64;
  const int wave = t >> 6, lane = t & 63;
  const int lo = lane & 15, hi = lane >> 4;

  // stage x tile, fp32 -> bf16
  #pragma unroll
  for (int i = 0; i < 8; ++i) {
    int f = t + 256*i;
    int r = f >> 5, c4 = (f & 31) * 4;
    float4 v = make_float4(0.f,0.f,0.f,0.f);
    if (n0 + r < NN) v = *(const float4*)(x + (size_t)(n0+r)*HIDD + c4);
    *(uint2*)&xs[r][c4] = make_uint2(pack2(v.x,v.y), pack2(v.z,v.w));
  }
  __syncthreads();

  fx4 acc[4][4] = {};
  const u16* wbase = Wt + (size_t)(cb + wave*64 + lo) * 128;
  #pragma unroll
  for (int s = 0; s < 4; ++s) {
    bfrag a[4], b[4];
    #pragma unroll
    for (int c = 0; c < 4; ++c)
      b[c] = *(const bfrag*)(wbase + c*16*128 + s*32 + hi*8);
    #pragma unroll
    for (int r = 0; r < 4; ++r)
      a[r] = *(const bfrag*)&xs[r*16 + lo][s*32 + hi*8];
    #pragma unroll
    for (int r = 0; r < 4; ++r)
      #pragma unroll
      for (int c = 0; c < 4; ++c)
        acc[r][c] = __builtin_amdgcn_mfma_f32_16x16x32_bf16(a[r], b[c], acc[r][c], 0, 0, 0);
  }

  // bias + pack to LDS (D layout: row = 16r + hi*4 + j, col = 64w + 16c + lo)
  float bb[4];
  #pragma unroll
  for (int c = 0; c < 4; ++c) bb[c] = bias[cb + wave*64 + c*16 + lo];
  #pragma unroll
  for (int r = 0; r < 4; ++r)
    #pragma unroll
    for (int c = 0; c < 4; ++c)
      #pragma unroll
      for (int j = 0; j < 4; ++j)
        outs[r*16 + hi*4 + j][wave*64 + c*16 + lo] = f2bf(acc[r][c][j] + bb[c]);
  __syncthreads();

  // coalesced 16B stores
  #pragma unroll
  for (int i = 0; i < 8; ++i) {
    int f = t + 256*i;
    int r = f >> 5, c8 = (f & 31) * 8;
    if (n0 + r < NN)
      *(uint4*)(qkvs + (size_t)(n0+r)*QS + cb + c8) = *(uint4*)&outs[r][c8];
  }
}

// K1b: qWe[n,h] = sum_c q[n,h,c]*We[h,c]
__global__ __launch_bounds__(256) void k1b_qwe(
    const u16* __restrict__ qkvs, const float* __restrict__ We,
    float* __restrict__ qWe)
{
  int wave = threadIdx.x >> 6, lane = threadIdx.x & 63;
  int n = blockIdx.x * 4 + wave;
  if (n >= NN) return;
  int h = lane >> 4, c0 = (lane & 15) * 8;
  uint4 qa = *(const uint4*)(qkvs + (size_t)n*QS + h*CCC + c0);
  const float* wr = We + h*CCC + c0;
  float s = bfl(qa.x)*wr[0] + bfh(qa.x)*wr[1]
          + bfl(qa.y)*wr[2] + bfh(qa.y)*wr[3]
          + bfl(qa.z)*wr[4] + bfh(qa.z)*wr[5]
          + bfl(qa.w)*wr[6] + bfh(qa.w)*wr[7];
  #pragma unroll
  for (int off = 8; off; off >>= 1) s += __shfl_xor(s, off);
  if ((lane & 15) == 0) qWe[(size_t)n*HH + h] = s;
}

// K2: p = exp(scale*(q[dst].k[src] + w_e*qWe[dst])); atomic denom
__global__ __launch_bounds__(256) void k2_alpha(
    const u16* __restrict__ qkvs,
    const int* __restrict__ ei, const float* __restrict__ ea,
    const float* __restrict__ qWe,
    float* __restrict__ pbuf, float* __restrict__ denom)
{
  int wave = threadIdx.x >> 6, lane = threadIdx.x & 63;
  int e = blockIdx.x * 4 + wave;
  if (e >= EE) return;
  int src = ei[e], dst = ei[EE + e];
  int h = lane >> 4, c0 = (lane & 15) * 8;
  uint4 qa = *(const uint4*)(qkvs + (size_t)dst*QS + h*CCC + c0);
  uint4 ka = *(const uint4*)(qkvs + (size_t)src*QS + 512 + h*CCC + c0);
  float s = bfl(qa.x)*bfl(ka.x) + bfh(qa.x)*bfh(ka.x)
          + bfl(qa.y)*bfl(ka.y) + bfh(qa.y)*bfh(ka.y)
          + bfl(qa.z)*bfl(ka.z) + bfh(qa.z)*bfh(ka.z)
          + bfl(qa.w)*bfl(ka.w) + bfh(qa.w)*bfh(ka.w);
  #pragma unroll
  for (int off = 8; off; off >>= 1) s += __shfl_xor(s, off);
  if ((lane & 15) == 0) {
    float alpha = (s + ea[e] * qWe[(size_t)dst*HH + h]) * SCALE;
    float p = expf(alpha);
    pbuf[(size_t)e*HH + h] = p;
    atomicAdd(&denom[(size_t)dst*HH + h], p);
  }
}

// K3: a = p/(denom+1e-16); agg[dst] += a*v[src] (pk bf16 atomics); sE[dst] += a*w_e
__global__ __launch_bounds__(256) void k3_msg(
    u16* __restrict__ qkvs, const int* __restrict__ ei,
    const float* __restrict__ ea, const float* __restrict__ pbuf,
    const float* __restrict__ denom, float* __restrict__ sE)
{
  int wave = threadIdx.x >> 6, lane = threadIdx.x & 63;
  int e = blockIdx.x * 4 + wave;
  if (e >= EE) return;
  int src = ei[e], dst = ei[EE + e];
  int h = lane >> 4, c0 = (lane & 15) * 8;
  float p = pbuf[(size_t)e*HH + h];
  float d = denom[(size_t)dst*HH + h];
  float a = p / (d + 1e-16f);
  uint4 va = *(const uint4*)(qkvs + (size_t)src*QS + 1024 + h*CCC + c0);
  u16* base = qkvs + (size_t)dst*QS + 1536 + h*CCC + c0;
  atomic_pk_bf16(base+0, a*bfl(va.x), a*bfh(va.x));
  atomic_pk_bf16(base+2, a*bfl(va.y), a*bfh(va.y));
  atomic_pk_bf16(base+4, a*bfl(va.z), a*bfh(va.z));
  atomic_pk_bf16(base+6, a*bfl(va.w), a*bfh(va.w));
  if ((lane & 15) == 0) atomicAdd(&sE[(size_t)dst*HH + h], a * ea[e]);
}

// K4: conv = agg + sE*We ; h = elu(conv@Wp + bp) ; y = x + h ; LayerNorm
// block tile 64 rows x 128 cols, MFMA over K=512 in 4 head-chunks
__global__ __launch_bounds__(256) void k4_mfma(
    const u16* __restrict__ qkvs, const float* __restrict__ sE,
    const float* __restrict__ We, const u16* __restrict__ Wpt,
    const float* __restrict__ bp, const float* __restrict__ gamma,
    const float* __restrict__ beta, const float* x_in, float* x_out)
{
  __shared__ u16 convs[64][136];
  __shared__ float ytile[64][132];
  __shared__ float mu_s[64], rs_s[64];
  const int t = threadIdx.x;
  const int n0 = blockIdx.x * 64;
  const int wave = t >> 6, lane = t & 63;
  const int lo = lane & 15, hi = lane >> 4;

  fx4 acc[8] = {};
  for (int h = 0; h < 4; ++h) {
    // stage conv chunk [64][128] bf16: agg + sE*We
    #pragma unroll
    for (int i = 0; i < 4; ++i) {
      int f = t + 256*i;
      int r = f >> 4, c8 = (f & 15) * 8;
      int n = n0 + r;
      uint4 o = make_uint4(0u,0u,0u,0u);
      if (n < NN) {
        uint4 av = *(const uint4*)(qkvs + (size_t)n*QS + 1536 + h*CCC + c8);
        float s = sE[(size_t)n*HH + h];
        const float* wv = We + h*CCC + c8;
        o.x = pack2(bfl(av.x)+s*wv[0], bfh(av.x)+s*wv[1]);
        o.y = pack2(bfl(av.y)+s*wv[2], bfh(av.y)+s*wv[3]);
        o.z = pack2(bfl(av.z)+s*wv[4], bfh(av.z)+s*wv[5]);
        o.w = pack2(bfl(av.w)+s*wv[6], bfh(av.w)+s*wv[7]);
      }
      *(uint4*)&convs[r][c8] = o;
    }
    __syncthreads();
    #pragma unroll
    for (int s = 0; s < 4; ++s) {
      bfrag a = *(const bfrag*)&convs[wave*16 + lo][s*32 + hi*8];
      #pragma unroll
      for (int c = 0; c < 8; ++c) {
        bfrag b = *(const bfrag*)(Wpt + (size_t)(c*16 + lo)*512 + h*128 + s*32 + hi*8);
        acc[c] = __builtin_amdgcn_mfma_f32_16x16x32_bf16(a, b, acc[c], 0, 0, 0);
      }
    }
    __syncthreads();
  }

  // epilogue: bias + ELU + residual -> ytile
  #pragma unroll
  for (int c = 0; c < 8; ++c) {
    float bb = bp[c*16 + lo];
    #pragma unroll
    for (int j = 0; j < 4; ++j) {
      int r = wave*16 + hi*4 + j;
      int n = n0 + r;
      float v = acc[c][j] + bb;
      v = v > 0.f ? v : expm1f(v);
      float xv = (n < NN) ? x_in[(size_t)n*HIDD + c*16 + lo] : 0.f;
      ytile[r][c*16 + lo] = xv + v;
    }
  }
  __syncthreads();

  // row stats: 4 threads per row, 32 cols each
  {
    int r = t >> 2, seg = t & 3;
    float s = 0.f, s2 = 0.f;
    #pragma unroll
    for (int j = 0; j < 32; ++j) {
      float y = ytile[r][seg*32 + j];
      s += y; s2 += y*y;
    }
    s += __shfl_xor(s, 1); s2 += __shfl_xor(s2, 1);
    s += __shfl_xor(s, 2); s2 += __shfl_xor(s2, 2);
    if (seg == 0) {
      float mu = s * (1.f/128.f);
      float var = s2 * (1.f/128.f) - mu*mu;
      mu_s[r] = mu;
      rs_s[r] = rsqrtf(var + 1e-5f);
    }
  }
  __syncthreads();

  #pragma unroll
  for (int i = 0; i < 8; ++i) {
    int f = t + 256*i;
    int r = f >> 5, c4 = (f & 31) * 4;
    int n = n0 + r;
    if (n >= NN) continue;
    float mu = mu_s[r], rs = rs_s[r];
    float4 g  = *(const float4*)(gamma + c4);
    float4 bt = *(const float4*)(beta + c4);
    float4 yv = *(float4*)&ytile[r][c4];
    *(float4*)(x_out + (size_t)n*HIDD + c4) = make_float4(
      (yv.x-mu)*rs*g.x + bt.x, (yv.y-mu)*rs*g.y + bt.y,
      (yv.z-mu)*rs*g.z + bt.z, (yv.w-mu)*rs*g.w + bt.w);
  }
}

extern "C" void kernel_launch(void* const* d_in, const int* in_sizes, int n_in,
                              void* d_out, int out_size, void* d_ws, size_t ws_size,
                              hipStream_t stream)
{
  const float* x    = (const float*)d_in[0];
  const int*   ei   = (const int*)d_in[1];
  const float* ea   = (const float*)d_in[2];
  const float* Wq   = (const float*)d_in[3];
  const float* bq   = (const float*)d_in[4];
  const float* Wk   = (const float*)d_in[5];
  const float* bk   = (const float*)d_in[6];
  const float* Wv   = (const float*)d_in[7];
  const float* bv   = (const float*)d_in[8];
  const float* We   = (const float*)d_in[9];
  const float* Wsk  = (const float*)d_in[10];
  const float* bsk  = (const float*)d_in[11];
  const float* Wp   = (const float*)d_in[12];
  const float* bp   = (const float*)d_in[13];
  const float* gamma= (const float*)d_in[14];
  const float* beta = (const float*)d_in[15];

  char* wsb = (char*)d_ws;
  size_t off = 0;
  auto alloc = [&](size_t bytes) -> void* {
    void* p = wsb + off;
    off += (bytes + 255) & ~(size_t)255;
    return p;
  };
  u16*   qkvs   = (u16*)  alloc((size_t)NN*QS*2);    // 204.8 MB (q|k|v|agg)
  float* pbuf   = (float*)alloc((size_t)EE*HH*4);    // 1.6 MB
  float* denomsE= (float*)alloc((size_t)2*NN*HH*4);  // 1.6 MB
  float* denom  = denomsE;
  float* sE     = denomsE + (size_t)NN*HH;
  float* qWe    = (float*)alloc((size_t)NN*HH*4);    // 0.8 MB
  u16*   Wt     = (u16*)  alloc((size_t)2048*128*2); // 512 KB
  u16*   Wpt    = (u16*)  alloc((size_t)128*512*2);  // 128 KB
  float* biasc  = (float*)alloc((size_t)2048*4);     // 8 KB
  float* xio    = (float*)d_out;                     // inter-layer x buffer

  const int gp   = (2048*128 + 128*512 + 2048 + 255)/256;
  const dim3 g1(8, (NN + 63)/64);
  const int gz   = (2*NN*HH + 255)/256;
  const int gb1b = (NN + 3)/4;
  const int ge   = (EE + 3)/4;
  const int g4   = (NN + 63)/64;

  for (int l = 0; l < LLL; ++l) {
    const float* Wq_l  = Wq  + (size_t)l*HIDD*HCC;
    const float* Wk_l  = Wk  + (size_t)l*HIDD*HCC;
    const float* Wv_l  = Wv  + (size_t)l*HIDD*HCC;
    const float* Wsk_l = Wsk + (size_t)l*HIDD*HCC;
    const float* bq_l  = bq  + (size_t)l*HCC;
    const float* bk_l  = bk  + (size_t)l*HCC;
    const float* bv_l  = bv  + (size_t)l*HCC;
    const float* bsk_l = bsk + (size_t)l*HCC;
    const float* We_l  = We  + (size_t)l*HCC;
    const float* Wp_l  = Wp  + (size_t)l*HCC*HIDD;
    const float* bp_l  = bp  + (size_t)l*HIDD;
    const float* g_l   = gamma + (size_t)l*HIDD;
    const float* b_l   = beta  + (size_t)l*HIDD;

    const float* xin = (l == 0) ? x : xio;

    kprep<<<gp, 256, 0, stream>>>(Wq_l, Wk_l, Wv_l, Wsk_l, bq_l, bk_l, bv_l, bsk_l,
                                  Wp_l, Wt, Wpt, biasc);
    k1_mfma<<<g1, 256, 0, stream>>>(xin, Wt, biasc, qkvs);
    k1b_qwe<<<gb1b, 256, 0, stream>>>(qkvs, We_l, qWe);
    kzero<<<gz, 256, 0, stream>>>(denomsE, 2*NN*HH);
    k2_alpha<<<ge, 256, 0, stream>>>(qkvs, ei, ea, qWe, pbuf, denom);
    k3_msg<<<ge, 256, 0, stream>>>(qkvs, ei, ea, pbuf, denom, sE);
    k4_mfma<<<g4, 256, 0, stream>>>(qkvs, sE, We_l, Wpt, bp_l, g_l, b_l, xin, xio);
  }
}

// Round 4
// 758.684 us; speedup vs baseline: 3.8563x; 2.2916x over previous
//
#include <hip/hip_runtime.h>

#define NN 50000
#define EE 100000
#define HIDD 128
#define HH 4
#define CCC 128
#define HCC 512
#define QS 2048            // row stride of fused qkvs buffer (u16 elements)
#define LLL 3
#define SCALE 0.08838834764831845f

typedef unsigned short u16;
typedef unsigned int u32;
typedef __attribute__((ext_vector_type(8))) short bfrag;   // 8 x bf16
typedef __attribute__((ext_vector_type(4))) float fx4;

__device__ __forceinline__ float bfl(u32 u){ return __uint_as_float(u << 16); }
__device__ __forceinline__ float bfh(u32 u){ return __uint_as_float(u & 0xffff0000u); }
__device__ __forceinline__ u16 f2bf(float f){
  u32 u = __float_as_uint(f);
  return (u16)((u + 0x7fffu + ((u >> 16) & 1u)) >> 16);
}
__device__ __forceinline__ u32 pack2(float a, float b){
  return (u32)f2bf(a) | ((u32)f2bf(b) << 16);
}

__global__ __launch_bounds__(256) void kzero(int* p, int n){
  int i = blockIdx.x * 256 + threadIdx.x;
  if (i < n) p[i] = 0;
}

// ---------------- CSR build (once per launch; graph identical across layers) ---
__global__ __launch_bounds__(256) void khist(const int* __restrict__ ei, int* __restrict__ counts){
  int e = blockIdx.x * 256 + threadIdx.x;
  if (e < EE) atomicAdd(&counts[ei[EE + e]], 1);
}

__global__ __launch_bounds__(256) void kscanA(const int* __restrict__ counts, int* __restrict__ bsum){
  __shared__ int sh[256];
  int t = threadIdx.x, i = blockIdx.x * 256 + t;
  sh[t] = (i < NN) ? counts[i] : 0;
  __syncthreads();
  #pragma unroll
  for (int off = 128; off; off >>= 1) {
    if (t < off) sh[t] += sh[t + off];
    __syncthreads();
  }
  if (t == 0) bsum[blockIdx.x] = sh[0];
}

__global__ __launch_bounds__(256) void kscanB(int* __restrict__ bsum, int nb){
  __shared__ int sh[256];
  int t = threadIdx.x;
  int v = (t < nb) ? bsum[t] : 0;
  sh[t] = v;
  __syncthreads();
  #pragma unroll
  for (int off = 1; off < 256; off <<= 1) {
    int a = (t >= off) ? sh[t - off] : 0;
    __syncthreads();
    sh[t] += a;
    __syncthreads();
  }
  if (t < nb) bsum[t] = sh[t] - v;   // exclusive
}

__global__ __launch_bounds__(256) void kscanC(const int* __restrict__ counts,
                                              const int* __restrict__ bsum,
                                              int* __restrict__ rowptr){
  __shared__ int sh[256];
  int t = threadIdx.x, i = blockIdx.x * 256 + t;
  int v = (i < NN) ? counts[i] : 0;
  sh[t] = v;
  __syncthreads();
  #pragma unroll
  for (int off = 1; off < 256; off <<= 1) {
    int a = (t >= off) ? sh[t - off] : 0;
    __syncthreads();
    sh[t] += a;
    __syncthreads();
  }
  if (i <= NN) rowptr[i] = bsum[blockIdx.x] + sh[t] - v;
}

__global__ __launch_bounds__(256) void kscatter(const int* __restrict__ ei,
                                                const float* __restrict__ ea,
                                                const int* __restrict__ rowptr,
                                                int* __restrict__ fill,
                                                int* __restrict__ csr_src,
                                                float* __restrict__ csr_ea){
  int e = blockIdx.x * 256 + threadIdx.x;
  if (e >= EE) return;
  int d = ei[EE + e];
  int pos = rowptr[d] + atomicAdd(&fill[d], 1);
  csr_src[pos] = ei[e];
  csr_ea[pos]  = ea[e];
}

// ---------------- per-layer weight prep -----------------
// Wt[2048][128] bf16 (transposed [Wq|Wk|Wv|Ws]), Wpt[128][512] bf16, bias_cat[2048]
__global__ __launch_bounds__(256) void kprep(
    const float* __restrict__ Wq, const float* __restrict__ Wk,
    const float* __restrict__ Wv, const float* __restrict__ Ws,
    const float* __restrict__ bq, const float* __restrict__ bk,
    const float* __restrict__ bv, const float* __restrict__ bs,
    const float* __restrict__ Wp,
    u16* __restrict__ Wt, u16* __restrict__ Wpt, float* __restrict__ bias_cat)
{
  int id = blockIdx.x * 256 + threadIdx.x;
  if (id < 2048*128) {
    int n = id >> 7, k = id & 127;
    int m = n >> 9, nc = n & 511;
    const float* W = (m==0)?Wq:(m==1)?Wk:(m==2)?Wv:Ws;
    Wt[id] = f2bf(W[(size_t)k*HCC + nc]);
  } else if (id < 2048*128 + 128*512) {
    int j = id - 2048*128;
    int n = j >> 9, k = j & 511;
    Wpt[j] = f2bf(Wp[(size_t)k*HIDD + n]);
  } else if (id < 2048*128 + 128*512 + 2048) {
    int n = id - (2048*128 + 128*512);
    int m = n >> 9, nc = n & 511;
    const float* b = (m==0)?bq:(m==1)?bk:(m==2)?bv:bs;
    bias_cat[n] = b[nc];
  }
}

// K1: qkvs[N,2048] = bf16( x[N,128] @ Wt^T + bias )   (q|k|v|skip fused)
__global__ __launch_bounds__(256) void k1_mfma(
    const float* __restrict__ x, const u16* __restrict__ Wt,
    const float* __restrict__ bias, u16* __restrict__ qkvs)
{
  __shared__ u16 xs[64][136];
  __shared__ u16 outs[64][264];
  const int t = threadIdx.x;
  const int cb = blockIdx.x * 256;
  const int n0 = blockIdx.y * 64;
  const int wave = t >> 6, lane = t & 63;
  const int lo = lane & 15, hi = lane >> 4;

  #pragma unroll
  for (int i = 0; i < 8; ++i) {
    int f = t + 256*i;
    int r = f >> 5, c4 = (f & 31) * 4;
    float4 v = make_float4(0.f,0.f,0.f,0.f);
    if (n0 + r < NN) v = *(const float4*)(x + (size_t)(n0+r)*HIDD + c4);
    *(uint2*)&xs[r][c4] = make_uint2(pack2(v.x,v.y), pack2(v.z,v.w));
  }
  __syncthreads();

  fx4 acc[4][4] = {};
  const u16* wbase = Wt + (size_t)(cb + wave*64 + lo) * 128;
  #pragma unroll
  for (int s = 0; s < 4; ++s) {
    bfrag a[4], b[4];
    #pragma unroll
    for (int c = 0; c < 4; ++c)
      b[c] = *(const bfrag*)(wbase + c*16*128 + s*32 + hi*8);
    #pragma unroll
    for (int r = 0; r < 4; ++r)
      a[r] = *(const bfrag*)&xs[r*16 + lo][s*32 + hi*8];
    #pragma unroll
    for (int r = 0; r < 4; ++r)
      #pragma unroll
      for (int c = 0; c < 4; ++c)
        acc[r][c] = __builtin_amdgcn_mfma_f32_16x16x32_bf16(a[r], b[c], acc[r][c], 0, 0, 0);
  }

  float bb[4];
  #pragma unroll
  for (int c = 0; c < 4; ++c) bb[c] = bias[cb + wave*64 + c*16 + lo];
  #pragma unroll
  for (int r = 0; r < 4; ++r)
    #pragma unroll
    for (int c = 0; c < 4; ++c)
      #pragma unroll
      for (int j = 0; j < 4; ++j)
        outs[r*16 + hi*4 + j][wave*64 + c*16 + lo] = f2bf(acc[r][c][j] + bb[c]);
  __syncthreads();

  #pragma unroll
  for (int i = 0; i < 8; ++i) {
    int f = t + 256*i;
    int r = f >> 5, c8 = (f & 31) * 8;
    if (n0 + r < NN)
      *(uint4*)(qkvs + (size_t)(n0+r)*QS + cb + c8) = *(uint4*)&outs[r][c8];
  }
}

// K23: fused edge attention per dst node (one wave per node).
// conv_row = skip + (Σ p·v[src])/D + ((Σ p·ea)/D)·We   with p = exp(scale·(q·k + ea·qWe))
__global__ __launch_bounds__(256) void k23_fused(
    u16* qkvs, const int* __restrict__ rowptr,
    const int* __restrict__ csr_src, const float* __restrict__ csr_ea,
    const float* __restrict__ We)
{
  int wave = threadIdx.x >> 6, lane = threadIdx.x & 63;
  int n = blockIdx.x * 4 + wave;
  if (n >= NN) return;
  int h = lane >> 4, c0 = (lane & 15) * 8;

  // q segment (8 elems) + We segment
  uint4 qa = *(const uint4*)(qkvs + (size_t)n*QS + h*CCC + c0);
  float qf[8] = {bfl(qa.x),bfh(qa.x),bfl(qa.y),bfh(qa.y),
                 bfl(qa.z),bfh(qa.z),bfl(qa.w),bfh(qa.w)};
  float4 w0 = *(const float4*)(We + h*CCC + c0);
  float4 w1 = *(const float4*)(We + h*CCC + c0 + 4);
  float wf[8] = {w0.x,w0.y,w0.z,w0.w,w1.x,w1.y,w1.z,w1.w};

  // qWe_h = q[h,:]·We[h,:]  (reduce within 16-lane group)
  float qw = qf[0]*wf[0]+qf[1]*wf[1]+qf[2]*wf[2]+qf[3]*wf[3]
           + qf[4]*wf[4]+qf[5]*wf[5]+qf[6]*wf[6]+qf[7]*wf[7];
  #pragma unroll
  for (int off = 8; off; off >>= 1) qw += __shfl_xor(qw, off);

  int beg = rowptr[n], end = rowptr[n+1];
  float accv[8] = {};
  float accp = 0.f, accw = 0.f;

  for (int i = beg; i < end; ++i) {
    int src = csr_src[i];
    float eav = csr_ea[i];
    uint4 ka = *(const uint4*)(qkvs + (size_t)src*QS + 512 + h*CCC + c0);
    float s = qf[0]*bfl(ka.x) + qf[1]*bfh(ka.x)
            + qf[2]*bfl(ka.y) + qf[3]*bfh(ka.y)
            + qf[4]*bfl(ka.z) + qf[5]*bfh(ka.z)
            + qf[6]*bfl(ka.w) + qf[7]*bfh(ka.w);
    #pragma unroll
    for (int off = 8; off; off >>= 1) s += __shfl_xor(s, off);
    float p = expf((s + eav * qw) * SCALE);
    uint4 va = *(const uint4*)(qkvs + (size_t)src*QS + 1024 + h*CCC + c0);
    accv[0] += p*bfl(va.x); accv[1] += p*bfh(va.x);
    accv[2] += p*bfl(va.y); accv[3] += p*bfh(va.y);
    accv[4] += p*bfl(va.z); accv[5] += p*bfh(va.z);
    accv[6] += p*bfl(va.w); accv[7] += p*bfh(va.w);
    accp += p; accw += p*eav;
  }

  float inv = 1.f / (accp + 1e-16f);
  float se  = accw * inv;
  u16* ap = qkvs + (size_t)n*QS + 1536 + h*CCC + c0;
  uint4 sk = *(const uint4*)ap;
  float o[8];
  o[0]=bfl(sk.x)+accv[0]*inv+se*wf[0]; o[1]=bfh(sk.x)+accv[1]*inv+se*wf[1];
  o[2]=bfl(sk.y)+accv[2]*inv+se*wf[2]; o[3]=bfh(sk.y)+accv[3]*inv+se*wf[3];
  o[4]=bfl(sk.z)+accv[4]*inv+se*wf[4]; o[5]=bfh(sk.z)+accv[5]*inv+se*wf[5];
  o[6]=bfl(sk.w)+accv[6]*inv+se*wf[6]; o[7]=bfh(sk.w)+accv[7]*inv+se*wf[7];
  *(uint4*)ap = make_uint4(pack2(o[0],o[1]), pack2(o[2],o[3]),
                           pack2(o[4],o[5]), pack2(o[6],o[7]));
}

// K4: h = elu(conv@Wp + bp) ; y = x + h ; LayerNorm
__global__ __launch_bounds__(256) void k4_mfma(
    const u16* __restrict__ qkvs, const u16* __restrict__ Wpt,
    const float* __restrict__ bp, const float* __restrict__ gamma,
    const float* __restrict__ beta, const float* x_in, float* x_out)
{
  __shared__ u16 convs[64][136];
  __shared__ float ytile[64][132];
  __shared__ float mu_s[64], rs_s[64];
  const int t = threadIdx.x;
  const int n0 = blockIdx.x * 64;
  const int wave = t >> 6, lane = t & 63;
  const int lo = lane & 15, hi = lane >> 4;

  fx4 acc[8] = {};
  for (int h = 0; h < 4; ++h) {
    #pragma unroll
    for (int i = 0; i < 4; ++i) {
      int f = t + 256*i;
      int r = f >> 4, c8 = (f & 15) * 8;
      int n = n0 + r;
      uint4 o = make_uint4(0u,0u,0u,0u);
      if (n < NN) o = *(const uint4*)(qkvs + (size_t)n*QS + 1536 + h*CCC + c8);
      *(uint4*)&convs[r][c8] = o;
    }
    __syncthreads();
    #pragma unroll
    for (int s = 0; s < 4; ++s) {
      bfrag a = *(const bfrag*)&convs[wave*16 + lo][s*32 + hi*8];
      #pragma unroll
      for (int c = 0; c < 8; ++c) {
        bfrag b = *(const bfrag*)(Wpt + (size_t)(c*16 + lo)*512 + h*128 + s*32 + hi*8);
        acc[c] = __builtin_amdgcn_mfma_f32_16x16x32_bf16(a, b, acc[c], 0, 0, 0);
      }
    }
    __syncthreads();
  }

  #pragma unroll
  for (int c = 0; c < 8; ++c) {
    float bb = bp[c*16 + lo];
    #pragma unroll
    for (int j = 0; j < 4; ++j) {
      int r = wave*16 + hi*4 + j;
      int n = n0 + r;
      float v = acc[c][j] + bb;
      v = v > 0.f ? v : expm1f(v);
      float xv = (n < NN) ? x_in[(size_t)n*HIDD + c*16 + lo] : 0.f;
      ytile[r][c*16 + lo] = xv + v;
    }
  }
  __syncthreads();

  {
    int r = t >> 2, seg = t & 3;
    float s = 0.f, s2 = 0.f;
    #pragma unroll
    for (int j = 0; j < 32; ++j) {
      float y = ytile[r][seg*32 + j];
      s += y; s2 += y*y;
    }
    s += __shfl_xor(s, 1); s2 += __shfl_xor(s2, 1);
    s += __shfl_xor(s, 2); s2 += __shfl_xor(s2, 2);
    if (seg == 0) {
      float mu = s * (1.f/128.f);
      float var = s2 * (1.f/128.f) - mu*mu;
      mu_s[r] = mu;
      rs_s[r] = rsqrtf(var + 1e-5f);
    }
  }
  __syncthreads();

  #pragma unroll
  for (int i = 0; i < 8; ++i) {
    int f = t + 256*i;
    int r = f >> 5, c4 = (f & 31) * 4;
    int n = n0 + r;
    if (n >= NN) continue;
    float mu = mu_s[r], rs = rs_s[r];
    float4 g  = *(const float4*)(gamma + c4);
    float4 bt = *(const float4*)(beta + c4);
    float4 yv = *(float4*)&ytile[r][c4];
    *(float4*)(x_out + (size_t)n*HIDD + c4) = make_float4(
      (yv.x-mu)*rs*g.x + bt.x, (yv.y-mu)*rs*g.y + bt.y,
      (yv.z-mu)*rs*g.z + bt.z, (yv.w-mu)*rs*g.w + bt.w);
  }
}

extern "C" void kernel_launch(void* const* d_in, const int* in_sizes, int n_in,
                              void* d_out, int out_size, void* d_ws, size_t ws_size,
                              hipStream_t stream)
{
  const float* x    = (const float*)d_in[0];
  const int*   ei   = (const int*)d_in[1];
  const float* ea   = (const float*)d_in[2];
  const float* Wq   = (const float*)d_in[3];
  const float* bq   = (const float*)d_in[4];
  const float* Wk   = (const float*)d_in[5];
  const float* bk   = (const float*)d_in[6];
  const float* Wv   = (const float*)d_in[7];
  const float* bv   = (const float*)d_in[8];
  const float* We   = (const float*)d_in[9];
  const float* Wsk  = (const float*)d_in[10];
  const float* bsk  = (const float*)d_in[11];
  const float* Wp   = (const float*)d_in[12];
  const float* bp   = (const float*)d_in[13];
  const float* gamma= (const float*)d_in[14];
  const float* beta = (const float*)d_in[15];

  char* wsb = (char*)d_ws;
  size_t off = 0;
  auto alloc = [&](size_t bytes) -> void* {
    void* p = wsb + off;
    off += (bytes + 255) & ~(size_t)255;
    return p;
  };
  u16*   qkvs    = (u16*)  alloc((size_t)NN*QS*2);     // 204.8 MB (q|k|v|conv)
  int*   rowptr  = (int*)  alloc((size_t)(NN+1)*4);
  int*   counts  = (int*)  alloc((size_t)NN*4);
  int*   fill    = (int*)  alloc((size_t)NN*4);
  int*   bsum    = (int*)  alloc((size_t)256*4);
  int*   csr_src = (int*)  alloc((size_t)EE*4);
  float* csr_ea  = (float*)alloc((size_t)EE*4);
  u16*   Wt      = (u16*)  alloc((size_t)2048*128*2);
  u16*   Wpt     = (u16*)  alloc((size_t)128*512*2);
  float* biasc   = (float*)alloc((size_t)2048*4);
  float* xio     = (float*)d_out;

  const int gn  = (NN + 255)/256;     // 196
  const int ge  = (EE + 255)/256;
  const int gp  = (2048*128 + 128*512 + 2048 + 255)/256;
  const dim3 g1(8, (NN + 63)/64);
  const int g23 = (NN + 3)/4;
  const int g4  = (NN + 63)/64;

  // ---- CSR build (graph constant across layers) ----
  kzero<<<gn, 256, 0, stream>>>(counts, NN);
  kzero<<<gn, 256, 0, stream>>>(fill, NN);
  khist<<<ge, 256, 0, stream>>>(ei, counts);
  kscanA<<<gn, 256, 0, stream>>>(counts, bsum);
  kscanB<<<1, 256, 0, stream>>>(bsum, gn);
  kscanC<<<gn, 256, 0, stream>>>(counts, bsum, rowptr);
  kscatter<<<ge, 256, 0, stream>>>(ei, ea, rowptr, fill, csr_src, csr_ea);

  for (int l = 0; l < LLL; ++l) {
    const float* Wq_l  = Wq  + (size_t)l*HIDD*HCC;
    const float* Wk_l  = Wk  + (size_t)l*HIDD*HCC;
    const float* Wv_l  = Wv  + (size_t)l*HIDD*HCC;
    const float* Wsk_l = Wsk + (size_t)l*HIDD*HCC;
    const float* bq_l  = bq  + (size_t)l*HCC;
    const float* bk_l  = bk  + (size_t)l*HCC;
    const float* bv_l  = bv  + (size_t)l*HCC;
    const float* bsk_l = bsk + (size_t)l*HCC;
    const float* We_l  = We  + (size_t)l*HCC;
    const float* Wp_l  = Wp  + (size_t)l*HCC*HIDD;
    const float* bp_l  = bp  + (size_t)l*HIDD;
    const float* g_l   = gamma + (size_t)l*HIDD;
    const float* b_l   = beta  + (size_t)l*HIDD;

    const float* xin = (l == 0) ? x : xio;

    kprep<<<gp, 256, 0, stream>>>(Wq_l, Wk_l, Wv_l, Wsk_l, bq_l, bk_l, bv_l, bsk_l,
                                  Wp_l, Wt, Wpt, biasc);
    k1_mfma<<<g1, 256, 0, stream>>>(xin, Wt, biasc, qkvs);
    k23_fused<<<g23, 256, 0, stream>>>(qkvs, rowptr, csr_src, csr_ea, We_l);
    k4_mfma<<<g4, 256, 0, stream>>>(qkvs, Wpt, bp_l, g_l, b_l, xin, xio);
  }
}